// Round 1
// baseline (585.861 us; speedup 1.0000x reference)
//
#include <hip/hip_runtime.h>

#define T_STEPS 120
#define NF_IN   180
#define H_DIM   128
#define G_DIM   512
#define K_FC    192
#define HP      136   // h_lds row stride (shorts)

#define L2E      1.4426950408889634f
#define TWO_L2E  2.8853900817779268f

typedef __attribute__((ext_vector_type(8))) short short8;
typedef __attribute__((ext_vector_type(4))) float f32x4;

// barrier WITHOUT vmcnt drain: LDS-ordering only. Global loads/stores stay in
// flight across steps (HIP __syncthreads drains vmcnt(0) -> ~900cyc/step stall).
#define LDS_BARRIER() asm volatile("s_waitcnt lgkmcnt(0)\ns_barrier" ::: "memory")

#if __has_builtin(__builtin_amdgcn_exp2f)
#define EXP2(x) __builtin_amdgcn_exp2f(x)
#else
#define EXP2(x) __expf((x) * 0.6931471805599453f)
#endif

__device__ __forceinline__ f32x4 mfma16(short8 a, short8 b, f32x4 c) {
    return __builtin_amdgcn_mfma_f32_16x16x32_bf16(a, b, c, 0, 0, 0);
}

__device__ __forceinline__ short f2bf(float x) {
    union { float f; unsigned u; } v; v.f = x;
    unsigned r = v.u + 0x7fffu + ((v.u >> 16) & 1u);
    return (short)(r >> 16);
}

// gate-sign AND log2e folded into weights at prep time:
//   i,f,o rows * (-log2e)  -> sigmoid(x) = rcp(1 + exp2(y))
//   g rows    * (+2*log2e) -> tanh(x)    = 1 - 2*rcp(1 + exp2(y))
__device__ __forceinline__ float sig2(float y) {
    return __builtin_amdgcn_rcpf(1.f + EXP2(y));
}
__device__ __forceinline__ float tanh2(float y) {
    return 1.f - 2.f * __builtin_amdgcn_rcpf(1.f + EXP2(y));
}

// ---------------- K1: weight prep (BN fold + bf16 + gate-sign/log2e folding) -
__global__ void prep_kernel(
    const float* __restrict__ fc_w, const float* __restrict__ fc_b,
    const float* __restrict__ bn_g, const float* __restrict__ bn_b,
    const float* __restrict__ bn_mean, const float* __restrict__ bn_var,
    const float* __restrict__ wih0, const float* __restrict__ whh0,
    const float* __restrict__ bih0, const float* __restrict__ bhh0,
    const float* __restrict__ wih1, const float* __restrict__ whh1,
    const float* __restrict__ bih1, const float* __restrict__ bhh1,
    short* __restrict__ fcw_o, float* __restrict__ fcb_o,
    float* __restrict__ bias0_o, float* __restrict__ bias1_o,
    short* __restrict__ wih0_o, short* __restrict__ whh0_o,
    short* __restrict__ wih1_o, short* __restrict__ whh1_o)
{
    int tid = blockIdx.x * blockDim.x + threadIdx.x;
    int stride = gridDim.x * blockDim.x;
    for (int i = tid; i < H_DIM * K_FC; i += stride) {
        int h = i / K_FC, f = i % K_FC;
        float s = bn_g[h] * rsqrtf(bn_var[h] + 1e-5f);
        float v = (f < NF_IN) ? fc_w[h * NF_IN + f] * s : 0.f;
        fcw_o[i] = f2bf(v);
    }
    for (int i = tid; i < H_DIM; i += stride) {
        float s = bn_g[i] * rsqrtf(bn_var[i] + 1e-5f);
        fcb_o[i] = (fc_b[i] - bn_mean[i]) * s + bn_b[i];
    }
    for (int i = tid; i < G_DIM; i += stride) {
        float sc = ((i >> 7) == 2) ? TWO_L2E : -L2E;
        bias0_o[i] = (bih0[i] + bhh0[i]) * sc;
        bias1_o[i] = (bih1[i] + bhh1[i]) * sc;
    }
    for (int i = tid; i < G_DIM * H_DIM; i += stride) {
        float sc = ((i >> 7) / H_DIM == 2) ? TWO_L2E : -L2E;
        wih0_o[i] = f2bf(wih0[i] * sc); whh0_o[i] = f2bf(whh0[i] * sc);
        wih1_o[i] = f2bf(wih1[i] * sc); whh1_o[i] = f2bf(whh1[i] * sc);
    }
}

// ---------------- K2: fused FC + BN + LeakyReLU (unchanged) ------------------
__global__ __launch_bounds__(256) void fc_kernel(
    const float* __restrict__ x, const short* __restrict__ fcw,
    const float* __restrict__ fcb, short* __restrict__ xfc)
{
    __shared__ short outs[120 * 132];
    const int b = blockIdx.x;
    const int tid = threadIdx.x;
    const int wave = tid >> 6, lane = tid & 63;
    const int m16 = lane & 15, q = lane >> 4;

    short8 af[2][6];
#pragma unroll
    for (int mi = 0; mi < 2; ++mi) {
        int t = (wave * 2 + mi) * 16 + m16;
        if (t > 119) t = 119;
        const float* xb = x + (size_t)b * (NF_IN * T_STEPS) + (size_t)q * 8 * T_STEPS + t;
#pragma unroll
        for (int kc = 0; kc < 6; ++kc) {
            union { short s[8]; short8 v; } u;
#pragma unroll
            for (int j = 0; j < 8; ++j) {
                int f = kc * 32 + q * 8 + j;
                float val = (f < NF_IN) ? xb[(kc * 32 + j) * T_STEPS] : 0.f;
                u.s[j] = f2bf(val);
            }
            af[mi][kc] = u.v;
        }
    }

    float fcb_v[8];
#pragma unroll
    for (int nt = 0; nt < 8; ++nt) fcb_v[nt] = fcb[nt * 16 + m16];

    f32x4 acc[2][8];
#pragma unroll
    for (int mi = 0; mi < 2; ++mi)
#pragma unroll
        for (int nt = 0; nt < 8; ++nt) acc[mi][nt] = (f32x4){0.f, 0.f, 0.f, 0.f};

#pragma unroll
    for (int nt = 0; nt < 8; ++nt) {
        short8 bf[6];
#pragma unroll
        for (int kc = 0; kc < 6; ++kc)
            bf[kc] = *(const short8*)(fcw + (nt * 16 + m16) * K_FC + kc * 32 + q * 8);
#pragma unroll
        for (int mi = 0; mi < 2; ++mi)
#pragma unroll
            for (int kc = 0; kc < 6; ++kc)
                acc[mi][nt] = mfma16(af[mi][kc], bf[kc], acc[mi][nt]);
    }

#pragma unroll
    for (int mi = 0; mi < 2; ++mi)
#pragma unroll
        for (int nt = 0; nt < 8; ++nt)
#pragma unroll
            for (int r = 0; r < 4; ++r) {
                int t = (wave * 2 + mi) * 16 + q * 4 + r;
                int h = nt * 16 + m16;
                float v = acc[mi][nt][r] + fcb_v[nt];
                v = (v >= 0.f) ? v : 0.01f * v;
                if (t < 120) outs[t * 132 + h] = f2bf(v);
            }
    __syncthreads();

    unsigned* dst = (unsigned*)xfc + (size_t)b * (T_STEPS * H_DIM / 2);
    const unsigned* srcs = (const unsigned*)outs;
    for (int i = tid; i < T_STEPS * H_DIM / 2; i += 256) {
        int t = i >> 6, c2 = i & 63;
        dst[i] = srcs[t * 66 + c2];
    }
}

// ---------------- K3: one LSTM layer -----------------------------------------
// 256 blocks x 512 thr (8 waves), 8 batch rows/block. Wave w owns dims
// [16w,16w+16) x 4 gates of BOTH matmuls (weights in VGPRs/AGPRs).
// LDS is used ONLY for h (cross-wave K=128 sharing): 4.3 KB total.
//   - proj accumulator P stays in registers (pair-packed: lanes q<2 = step t1,
//     lanes q>=2 = t1+1); the t1+1 half reaches lanes q<2 via 16 shfl_xor(32).
//   - xp is consumed as the rec MFMA's C-init (y-adds happen inside the MFMA).
//   - gate/cell update runs in the MFMA C layout: lanes q<2 hold 4 batch rows
//     x 1 dim with all 4 gates in-lane -> no rc_lds transpose round-trip.
__global__ __launch_bounds__(512, 2) void lstm_kernel(
    const short* h_in, const short* __restrict__ wih,
    const short* __restrict__ whh, const float* __restrict__ bias,
    short* h_out, float* __restrict__ fout)
{
    __shared__ short h_lds[2 * 8 * HP];

    const int tid = threadIdx.x;
    const int w = tid >> 6, lane = tid & 63;
    const int m16 = lane & 15, q = lane >> 4, m8 = m16 & 7;
    const int b0 = blockIdx.x * 8;

    // zero BOTH h buffers (8*HP uints == 16*HP shorts == whole array)
    for (int i = tid; i < 8 * HP; i += 512) ((unsigned*)h_lds)[i] = 0u;

    short8 whf[4][4], wif[4][4];
    float bias_v[4];
#pragma unroll
    for (int g = 0; g < 4; ++g) {
        int n = g * 128 + w * 16 + m16;
        bias_v[g] = bias[n];
#pragma unroll
        for (int kc = 0; kc < 4; ++kc) {
            whf[g][kc] = *(const short8*)(whh + n * H_DIM + kc * 32 + q * 8);
            wif[g][kc] = *(const short8*)(wih + n * H_DIM + kc * 32 + q * 8);
        }
    }

    float c[4] = {0.f, 0.f, 0.f, 0.f};   // cell state: lanes q<2, batch q*4+r
    f32x4 P[4];                          // in-reg xp pair (incl. bias)

    // pair-load A-frags for proj(t1, t1+1): rows 0-7 <- t1, rows 8-15 <- t1+1
    auto loadPair = [&](short8 ax[4], int t1) {
        int t = t1 + (m16 >> 3);
        if (t > T_STEPS - 1) t = T_STEPS - 1;
        const short* src = h_in + ((size_t)(b0 + m8) * T_STEPS + t) * H_DIM + q * 8;
#pragma unroll
        for (int kc = 0; kc < 4; ++kc) ax[kc] = *(const short8*)(src + kc * 32);
    };

    // proj for a pair -> registers P (no LDS)
    auto projPairR = [&](const short8 ax[4]) {
#pragma unroll
        for (int g = 0; g < 4; ++g) {
            float bv = bias_v[g];
            f32x4 acc = (f32x4){bv, bv, bv, bv};
#pragma unroll
            for (int kc = 0; kc < 4; ++kc) acc = mfma16(ax[kc], wif[g][kc], acc);
            P[g] = acc;
        }
    };

    // rec matmul (C-init = xp) + in-register gate/cell update + h write.
    // xp[g] must hold step-s xp in rows 0-7 (lanes q<2).
    auto recUpdate = [&](int s, int rb, int hb, const f32x4 xp0, const f32x4 xp1,
                         const f32x4 xp2, const f32x4 xp3) {
        const short* rbp = h_lds + rb * (8 * HP) + m8 * HP + q * 8;
        short8 ar[4];
#pragma unroll
        for (int kc = 0; kc < 4; ++kc) ar[kc] = *(const short8*)(rbp + kc * 32);
        f32x4 a0 = xp0, a1 = xp1, a2 = xp2, a3 = xp3;
#pragma unroll
        for (int kc = 0; kc < 4; ++kc) {
            a0 = mfma16(ar[kc], whf[0][kc], a0);
            a1 = mfma16(ar[kc], whf[1][kc], a1);
            a2 = mfma16(ar[kc], whf[2][kc], a2);
            a3 = mfma16(ar[kc], whf[3][kc], a3);
        }
        // lanes q<2 hold batch rows q*4+r; q>=2 compute harmless garbage
        float hv[4];
#pragma unroll
        for (int r = 0; r < 4; ++r) {
            float i_ = sig2(a0[r]);
            float f_ = sig2(a1[r]);
            float g_ = tanh2(a2[r]);
            float o_ = sig2(a3[r]);
            c[r] = f_ * c[r] + i_ * g_;
            hv[r] = o_ * tanh2(c[r] * TWO_L2E);
        }
        const int dim = w * 16 + m16;
        if (q < 2) {
            short* hw = h_lds + hb * (8 * HP) + (q * 4) * HP + dim;
#pragma unroll
            for (int r = 0; r < 4; ++r) hw[r * HP] = f2bf(hv[r]);
        }
        if (fout != nullptr && s == T_STEPS - 1 && q < 2) {
#pragma unroll
            for (int r = 0; r < 4; ++r)
                fout[(size_t)(b0 + q * 4 + r) * H_DIM + dim] = hv[r];
        }
    };

    auto exportH = [&](int s, int hb) {   // coalesced h(s) -> global
        int row = tid >> 6, c2 = tid & 63;
        unsigned v = ((const unsigned*)h_lds)[hb * (4 * HP) + row * (HP / 2) + c2];
        ((unsigned*)h_out)[((size_t)(b0 + row) * T_STEPS + s) * (H_DIM / 2) + c2] = v;
    };

    // prologue: P <- xp(0) in BOTH halves (every A row reads x at t=0),
    // so the first even step's shfl_xor hands xp(0) to lanes q<2.
    {
        short8 ax0[4];
        const short* src = h_in + (size_t)(b0 + m8) * T_STEPS * H_DIM + q * 8;
#pragma unroll
        for (int kc = 0; kc < 4; ++kc) ax0[kc] = *(const short8*)(src + kc * 32);
        projPairR(ax0);
    }
    short8 axc[4];
    loadPair(axc, 1);
    LDS_BARRIER();

    for (int it = 0; it < T_STEPS / 2; ++it) {
        const int s = 2 * it;
        // ---- even step: shfl xp, rec+update, proj(s+1,s+2), prefetch --------
        short8 axn[4];
        loadPair(axn, s + 3);
        f32x4 xps[4];
#pragma unroll
        for (int g = 0; g < 4; ++g)
#pragma unroll
            for (int e = 0; e < 4; ++e) xps[g][e] = __shfl_xor(P[g][e], 32);
        recUpdate(s, 1, 0, xps[0], xps[1], xps[2], xps[3]);  // h(s-1) buf1 -> h(s) buf0
        projPairR(axc);                                      // P <- xp(s+1), xp(s+2)
        if (h_out != nullptr && s >= 1) exportH(s - 1, 1);
        LDS_BARRIER();
        // ---- odd step: rec+update (xp(s+1) already in lanes q<2 of P) -------
        recUpdate(s + 1, 0, 1, P[0], P[1], P[2], P[3]);      // h(s) buf0 -> h(s+1) buf1
#pragma unroll
        for (int kc = 0; kc < 4; ++kc) axc[kc] = axn[kc];
        if (h_out != nullptr) exportH(s, 0);
        LDS_BARRIER();
    }
    if (h_out != nullptr) exportH(T_STEPS - 1, 1);
}

// ---------------- launch ----------------
static constexpr size_t OFF_FCW  = 0;
static constexpr size_t OFF_FCB  = 49152;
static constexpr size_t OFF_B0   = 49664;
static constexpr size_t OFF_B1   = 51712;
static constexpr size_t OFF_WIH0 = 53760;
static constexpr size_t OFF_WHH0 = 184832;
static constexpr size_t OFF_WIH1 = 315904;
static constexpr size_t OFF_WHH1 = 446976;
static constexpr size_t OFF_BUFA = 578048;

extern "C" void kernel_launch(void* const* d_in, const int* in_sizes, int n_in,
                              void* d_out, int out_size, void* d_ws, size_t ws_size,
                              hipStream_t stream) {
    const float* x       = (const float*)d_in[0];
    const float* fc_w    = (const float*)d_in[1];
    const float* fc_b    = (const float*)d_in[2];
    const float* bn_g    = (const float*)d_in[3];
    const float* bn_b    = (const float*)d_in[4];
    const float* bn_mean = (const float*)d_in[5];
    const float* bn_var  = (const float*)d_in[6];
    const float* wih0    = (const float*)d_in[7];
    const float* whh0    = (const float*)d_in[8];
    const float* bih0    = (const float*)d_in[9];
    const float* bhh0    = (const float*)d_in[10];
    const float* wih1    = (const float*)d_in[11];
    const float* whh1    = (const float*)d_in[12];
    const float* bih1    = (const float*)d_in[13];
    const float* bhh1    = (const float*)d_in[14];

    const int B = in_sizes[0] / (NF_IN * T_STEPS);   // 2048

    char* ws = (char*)d_ws;
    short* fcw   = (short*)(ws + OFF_FCW);
    float* fcb   = (float*)(ws + OFF_FCB);
    float* bias0 = (float*)(ws + OFF_B0);
    float* bias1 = (float*)(ws + OFF_B1);
    short* wih0b = (short*)(ws + OFF_WIH0);
    short* whh0b = (short*)(ws + OFF_WHH0);
    short* wih1b = (short*)(ws + OFF_WIH1);
    short* whh1b = (short*)(ws + OFF_WHH1);
    short* bufA  = (short*)(ws + OFF_BUFA);

    prep_kernel<<<256, 256, 0, stream>>>(
        fc_w, fc_b, bn_g, bn_b, bn_mean, bn_var,
        wih0, whh0, bih0, bhh0, wih1, whh1, bih1, bhh1,
        fcw, fcb, bias0, bias1, wih0b, whh0b, wih1b, whh1b);

    fc_kernel<<<B, 256, 0, stream>>>(x, fcw, fcb, bufA);

    lstm_kernel<<<B / 8, 512, 0, stream>>>(bufA, wih0b, whh0b, bias0, bufA, nullptr);
    lstm_kernel<<<B / 8, 512, 0, stream>>>(bufA, wih1b, whh1b, bias1, nullptr, (float*)d_out);
}

// Round 2
// 560.856 us; speedup vs baseline: 1.0446x; 1.0446x over previous
//
#include <hip/hip_runtime.h>

#define T_STEPS 120
#define NF_IN   180
#define H_DIM   128
#define G_DIM   512
#define K_FC    192
#define HP      136   // h_lds row stride (shorts)

#define L2E      1.4426950408889634f
#define TWO_L2E  2.8853900817779268f

typedef __attribute__((ext_vector_type(8))) short short8;
typedef __attribute__((ext_vector_type(4))) float f32x4;

// barrier WITHOUT vmcnt drain: LDS-ordering only. Global loads/stores stay in
// flight across steps (HIP __syncthreads drains vmcnt(0) -> ~900cyc/step stall).
#define LDS_BARRIER() asm volatile("s_waitcnt lgkmcnt(0)\ns_barrier" ::: "memory")

#if __has_builtin(__builtin_amdgcn_exp2f)
#define EXP2(x) __builtin_amdgcn_exp2f(x)
#else
#define EXP2(x) __expf((x) * 0.6931471805599453f)
#endif

__device__ __forceinline__ f32x4 mfma16(short8 a, short8 b, f32x4 c) {
    return __builtin_amdgcn_mfma_f32_16x16x32_bf16(a, b, c, 0, 0, 0);
}

__device__ __forceinline__ short f2bf(float x) {
    union { float f; unsigned u; } v; v.f = x;
    unsigned r = v.u + 0x7fffu + ((v.u >> 16) & 1u);
    return (short)(r >> 16);
}

// gate-sign AND log2e folded into weights at prep time:
//   i,f,o rows * (-log2e)  -> sigmoid(x) = rcp(1 + exp2(y))
//   g rows    * (+2*log2e) -> tanh(x)    = 1 - 2*rcp(1 + exp2(y))
__device__ __forceinline__ float sig2(float y) {
    return __builtin_amdgcn_rcpf(1.f + EXP2(y));
}
__device__ __forceinline__ float tanh2(float y) {
    return 1.f - 2.f * __builtin_amdgcn_rcpf(1.f + EXP2(y));
}

// ---------------- K1: weight prep (BN fold + bf16 + gate-sign/log2e folding) -
__global__ void prep_kernel(
    const float* __restrict__ fc_w, const float* __restrict__ fc_b,
    const float* __restrict__ bn_g, const float* __restrict__ bn_b,
    const float* __restrict__ bn_mean, const float* __restrict__ bn_var,
    const float* __restrict__ wih0, const float* __restrict__ whh0,
    const float* __restrict__ bih0, const float* __restrict__ bhh0,
    const float* __restrict__ wih1, const float* __restrict__ whh1,
    const float* __restrict__ bih1, const float* __restrict__ bhh1,
    short* __restrict__ fcw_o, float* __restrict__ fcb_o,
    float* __restrict__ bias0_o, float* __restrict__ bias1_o,
    short* __restrict__ wih0_o, short* __restrict__ whh0_o,
    short* __restrict__ wih1_o, short* __restrict__ whh1_o)
{
    int tid = blockIdx.x * blockDim.x + threadIdx.x;
    int stride = gridDim.x * blockDim.x;
    for (int i = tid; i < H_DIM * K_FC; i += stride) {
        int h = i / K_FC, f = i % K_FC;
        float s = bn_g[h] * rsqrtf(bn_var[h] + 1e-5f);
        float v = (f < NF_IN) ? fc_w[h * NF_IN + f] * s : 0.f;
        fcw_o[i] = f2bf(v);
    }
    for (int i = tid; i < H_DIM; i += stride) {
        float s = bn_g[i] * rsqrtf(bn_var[i] + 1e-5f);
        fcb_o[i] = (fc_b[i] - bn_mean[i]) * s + bn_b[i];
    }
    for (int i = tid; i < G_DIM; i += stride) {
        float sc = ((i >> 7) == 2) ? TWO_L2E : -L2E;
        bias0_o[i] = (bih0[i] + bhh0[i]) * sc;
        bias1_o[i] = (bih1[i] + bhh1[i]) * sc;
    }
    for (int i = tid; i < G_DIM * H_DIM; i += stride) {
        float sc = ((i >> 7) / H_DIM == 2) ? TWO_L2E : -L2E;
        wih0_o[i] = f2bf(wih0[i] * sc); whh0_o[i] = f2bf(whh0[i] * sc);
        wih1_o[i] = f2bf(wih1[i] * sc); whh1_o[i] = f2bf(whh1[i] * sc);
    }
}

// ---------------- K2: fused FC + BN + LeakyReLU (unchanged) ------------------
__global__ __launch_bounds__(256) void fc_kernel(
    const float* __restrict__ x, const short* __restrict__ fcw,
    const float* __restrict__ fcb, short* __restrict__ xfc)
{
    __shared__ short outs[120 * 132];
    const int b = blockIdx.x;
    const int tid = threadIdx.x;
    const int wave = tid >> 6, lane = tid & 63;
    const int m16 = lane & 15, q = lane >> 4;

    short8 af[2][6];
#pragma unroll
    for (int mi = 0; mi < 2; ++mi) {
        int t = (wave * 2 + mi) * 16 + m16;
        if (t > 119) t = 119;
        const float* xb = x + (size_t)b * (NF_IN * T_STEPS) + (size_t)q * 8 * T_STEPS + t;
#pragma unroll
        for (int kc = 0; kc < 6; ++kc) {
            union { short s[8]; short8 v; } u;
#pragma unroll
            for (int j = 0; j < 8; ++j) {
                int f = kc * 32 + q * 8 + j;
                float val = (f < NF_IN) ? xb[(kc * 32 + j) * T_STEPS] : 0.f;
                u.s[j] = f2bf(val);
            }
            af[mi][kc] = u.v;
        }
    }

    float fcb_v[8];
#pragma unroll
    for (int nt = 0; nt < 8; ++nt) fcb_v[nt] = fcb[nt * 16 + m16];

    f32x4 acc[2][8];
#pragma unroll
    for (int mi = 0; mi < 2; ++mi)
#pragma unroll
        for (int nt = 0; nt < 8; ++nt) acc[mi][nt] = (f32x4){0.f, 0.f, 0.f, 0.f};

#pragma unroll
    for (int nt = 0; nt < 8; ++nt) {
        short8 bf[6];
#pragma unroll
        for (int kc = 0; kc < 6; ++kc)
            bf[kc] = *(const short8*)(fcw + (nt * 16 + m16) * K_FC + kc * 32 + q * 8);
#pragma unroll
        for (int mi = 0; mi < 2; ++mi)
#pragma unroll
            for (int kc = 0; kc < 6; ++kc)
                acc[mi][nt] = mfma16(af[mi][kc], bf[kc], acc[mi][nt]);
    }

#pragma unroll
    for (int mi = 0; mi < 2; ++mi)
#pragma unroll
        for (int nt = 0; nt < 8; ++nt)
#pragma unroll
            for (int r = 0; r < 4; ++r) {
                int t = (wave * 2 + mi) * 16 + q * 4 + r;
                int h = nt * 16 + m16;
                float v = acc[mi][nt][r] + fcb_v[nt];
                v = (v >= 0.f) ? v : 0.01f * v;
                if (t < 120) outs[t * 132 + h] = f2bf(v);
            }
    __syncthreads();

    unsigned* dst = (unsigned*)xfc + (size_t)b * (T_STEPS * H_DIM / 2);
    const unsigned* srcs = (const unsigned*)outs;
    for (int i = tid; i < T_STEPS * H_DIM / 2; i += 256) {
        int t = i >> 6, c2 = i & 63;
        dst[i] = srcs[t * 66 + c2];
    }
}

// ---------------- K3: one LSTM layer -----------------------------------------
// 256 blocks x 512 thr (8 waves), 8 batch rows/block. Wave w owns dims
// [16w,16w+16) x 4 gates of BOTH matmuls (weights in VGPRs/AGPRs).
// LDS is used ONLY for h (cross-wave K=128 sharing): 4.3 KB total.
// Critical-path discipline (this round): recUpdate issues IMMEDIATELY after
// each barrier; the 16 shfl_xor for the cross-half xp exchange are hoisted to
// right after projPairR (consumed 2 phases later -> ds_bpermute latency fully
// off-chain); proj/loadPair/exportH all sit in the post-chain slack.
__global__ __launch_bounds__(512, 2) void lstm_kernel(
    const short* h_in, const short* __restrict__ wih,
    const short* __restrict__ whh, const float* __restrict__ bias,
    short* h_out, float* __restrict__ fout)
{
    __shared__ short h_lds[2 * 8 * HP];

    const int tid = threadIdx.x;
    const int w = tid >> 6, lane = tid & 63;
    const int m16 = lane & 15, q = lane >> 4, m8 = m16 & 7;
    const int b0 = blockIdx.x * 8;

    // zero BOTH h buffers (8*HP uints == 16*HP shorts == whole array)
    for (int i = tid; i < 8 * HP; i += 512) ((unsigned*)h_lds)[i] = 0u;

    short8 whf[4][4], wif[4][4];
    float bias_v[4];
#pragma unroll
    for (int g = 0; g < 4; ++g) {
        int n = g * 128 + w * 16 + m16;
        bias_v[g] = bias[n];
#pragma unroll
        for (int kc = 0; kc < 4; ++kc) {
            whf[g][kc] = *(const short8*)(whh + n * H_DIM + kc * 32 + q * 8);
            wif[g][kc] = *(const short8*)(wih + n * H_DIM + kc * 32 + q * 8);
        }
    }

    float c[4] = {0.f, 0.f, 0.f, 0.f};   // cell*2log2e: lanes q<2, batch q*4+r
    f32x4 P[4];                          // in-reg xp pair (incl. bias)
    f32x4 xps[4];                        // pre-shuffled xp for the even step

    // pair-load A-frags for proj(t1, t1+1): rows 0-7 <- t1, rows 8-15 <- t1+1
    auto loadPair = [&](short8 ax[4], int t1) {
        int t = t1 + (m16 >> 3);
        if (t > T_STEPS - 1) t = T_STEPS - 1;
        const short* src = h_in + ((size_t)(b0 + m8) * T_STEPS + t) * H_DIM + q * 8;
#pragma unroll
        for (int kc = 0; kc < 4; ++kc) ax[kc] = *(const short8*)(src + kc * 32);
    };

    // proj for a pair -> registers P (no LDS)
    auto projPairR = [&](const short8 ax[4]) {
#pragma unroll
        for (int g = 0; g < 4; ++g) {
            float bv = bias_v[g];
            f32x4 acc = (f32x4){bv, bv, bv, bv};
#pragma unroll
            for (int kc = 0; kc < 4; ++kc) acc = mfma16(ax[kc], wif[g][kc], acc);
            P[g] = acc;
        }
    };

    // rec matmul (C-init = xp) + in-register gate/cell update + h write.
    // xp[g] must hold step-s xp in rows 0-7 (lanes q<2).
    // c is kept pre-scaled by 2*log2e: g-gate output is scaled at its fma, so
    // the h tail is tanh2(c) directly (one fewer dependent op).
    auto recUpdate = [&](int s, int rb, int hb, const f32x4 xp0, const f32x4 xp1,
                         const f32x4 xp2, const f32x4 xp3) {
        const short* rbp = h_lds + rb * (8 * HP) + m8 * HP + q * 8;
        short8 ar[4];
#pragma unroll
        for (int kc = 0; kc < 4; ++kc) ar[kc] = *(const short8*)(rbp + kc * 32);
        f32x4 a0 = xp0, a1 = xp1, a2 = xp2, a3 = xp3;
#pragma unroll
        for (int kc = 0; kc < 4; ++kc) {
            a0 = mfma16(ar[kc], whf[0][kc], a0);
            a1 = mfma16(ar[kc], whf[1][kc], a1);
            a2 = mfma16(ar[kc], whf[2][kc], a2);
            a3 = mfma16(ar[kc], whf[3][kc], a3);
        }
        // lanes q<2 hold batch rows q*4+r; q>=2 compute harmless garbage
        float hv[4];
#pragma unroll
        for (int r = 0; r < 4; ++r) {
            float i_ = sig2(a0[r]);
            float f_ = sig2(a1[r]);
            // g scaled by 2*log2e: TWO_L2E * (1 - 2*rcp) = fma(-2*TWO_L2E, rcp, TWO_L2E)
            float g_ = __builtin_fmaf(-2.f * TWO_L2E,
                                      __builtin_amdgcn_rcpf(1.f + EXP2(a2[r])),
                                      TWO_L2E);
            float o_ = sig2(a3[r]);
            c[r] = f_ * c[r] + i_ * g_;
            hv[r] = o_ * tanh2(c[r]);
        }
        const int dim = w * 16 + m16;
        if (q < 2) {
            short* hw = h_lds + hb * (8 * HP) + (q * 4) * HP + dim;
#pragma unroll
            for (int r = 0; r < 4; ++r) hw[r * HP] = f2bf(hv[r]);
        }
        if (fout != nullptr && s == T_STEPS - 1 && q < 2) {
#pragma unroll
            for (int r = 0; r < 4; ++r)
                fout[(size_t)(b0 + q * 4 + r) * H_DIM + dim] = hv[r];
        }
    };

    auto exportH = [&](int s, int hb) {   // coalesced h(s) -> global
        int row = tid >> 6, c2 = tid & 63;
        unsigned v = ((const unsigned*)h_lds)[hb * (4 * HP) + row * (HP / 2) + c2];
        ((unsigned*)h_out)[((size_t)(b0 + row) * T_STEPS + s) * (H_DIM / 2) + c2] = v;
    };

    // prologue: P <- xp(0) in BOTH halves (every A row reads x at t=0);
    // xps <- P directly (all lanes already hold xp(0), no shuffle needed).
    {
        short8 ax0[4];
        const short* src = h_in + (size_t)(b0 + m8) * T_STEPS * H_DIM + q * 8;
#pragma unroll
        for (int kc = 0; kc < 4; ++kc) ax0[kc] = *(const short8*)(src + kc * 32);
        projPairR(ax0);
    }
#pragma unroll
    for (int g = 0; g < 4; ++g) xps[g] = P[g];
    short8 axc[4];
    loadPair(axc, 1);
    LDS_BARRIER();

    for (int it = 0; it < T_STEPS / 2; ++it) {
        const int s = 2 * it;
        // ---- even phase: chain first, slack work after ----------------------
        recUpdate(s, 1, 0, xps[0], xps[1], xps[2], xps[3]);  // h(s-1) buf1 -> h(s) buf0
        projPairR(axc);                                      // P <- xp(s+1), xp(s+2)
#pragma unroll
        for (int g = 0; g < 4; ++g)                          // hoisted shuffle:
#pragma unroll
            for (int e = 0; e < 4; ++e)                      // xp(s+2) -> lanes q<2,
                xps[g][e] = __shfl_xor(P[g][e], 32);         // consumed at phase s+2
        short8 axn[4];
        loadPair(axn, s + 3);
        if (h_out != nullptr && s >= 1) exportH(s - 1, 1);
        LDS_BARRIER();
        // ---- odd phase: chain first ----------------------------------------
        recUpdate(s + 1, 0, 1, P[0], P[1], P[2], P[3]);      // h(s) buf0 -> h(s+1) buf1
#pragma unroll
        for (int kc = 0; kc < 4; ++kc) axc[kc] = axn[kc];
        if (h_out != nullptr) exportH(s, 0);
        LDS_BARRIER();
    }
    if (h_out != nullptr) exportH(T_STEPS - 1, 1);
}

// ---------------- launch ----------------
static constexpr size_t OFF_FCW  = 0;
static constexpr size_t OFF_FCB  = 49152;
static constexpr size_t OFF_B0   = 49664;
static constexpr size_t OFF_B1   = 51712;
static constexpr size_t OFF_WIH0 = 53760;
static constexpr size_t OFF_WHH0 = 184832;
static constexpr size_t OFF_WIH1 = 315904;
static constexpr size_t OFF_WHH1 = 446976;
static constexpr size_t OFF_BUFA = 578048;

extern "C" void kernel_launch(void* const* d_in, const int* in_sizes, int n_in,
                              void* d_out, int out_size, void* d_ws, size_t ws_size,
                              hipStream_t stream) {
    const float* x       = (const float*)d_in[0];
    const float* fc_w    = (const float*)d_in[1];
    const float* fc_b    = (const float*)d_in[2];
    const float* bn_g    = (const float*)d_in[3];
    const float* bn_b    = (const float*)d_in[4];
    const float* bn_mean = (const float*)d_in[5];
    const float* bn_var  = (const float*)d_in[6];
    const float* wih0    = (const float*)d_in[7];
    const float* whh0    = (const float*)d_in[8];
    const float* bih0    = (const float*)d_in[9];
    const float* bhh0    = (const float*)d_in[10];
    const float* wih1    = (const float*)d_in[11];
    const float* whh1    = (const float*)d_in[12];
    const float* bih1    = (const float*)d_in[13];
    const float* bhh1    = (const float*)d_in[14];

    const int B = in_sizes[0] / (NF_IN * T_STEPS);   // 2048

    char* ws = (char*)d_ws;
    short* fcw   = (short*)(ws + OFF_FCW);
    float* fcb   = (float*)(ws + OFF_FCB);
    float* bias0 = (float*)(ws + OFF_B0);
    float* bias1 = (float*)(ws + OFF_B1);
    short* wih0b = (short*)(ws + OFF_WIH0);
    short* whh0b = (short*)(ws + OFF_WHH0);
    short* wih1b = (short*)(ws + OFF_WIH1);
    short* whh1b = (short*)(ws + OFF_WHH1);
    short* bufA  = (short*)(ws + OFF_BUFA);

    prep_kernel<<<256, 256, 0, stream>>>(
        fc_w, fc_b, bn_g, bn_b, bn_mean, bn_var,
        wih0, whh0, bih0, bhh0, wih1, whh1, bih1, bhh1,
        fcw, fcb, bias0, bias1, wih0b, whh0b, wih1b, whh1b);

    fc_kernel<<<B, 256, 0, stream>>>(x, fcw, fcb, bufA);

    lstm_kernel<<<B / 8, 512, 0, stream>>>(bufA, wih0b, whh0b, bias0, bufA, nullptr);
    lstm_kernel<<<B / 8, 512, 0, stream>>>(bufA, wih1b, whh1b, bias1, nullptr, (float*)d_out);
}